// Round 20
// baseline (2043.500 us; speedup 1.0000x reference)
//
#include <hip/hip_runtime.h>

typedef __attribute__((ext_vector_type(4))) float f32x4;
typedef __attribute__((ext_vector_type(4))) unsigned int u32x4;
typedef __attribute__((ext_vector_type(4))) int i32x4;
typedef __attribute__((ext_vector_type(8))) int i32x8;
typedef __attribute__((ext_vector_type(4))) unsigned short u16x4;
typedef unsigned char u8;
typedef unsigned short u16;
typedef unsigned int u32;

#define MBYTE (1024*1024)
#define TTOK 16384
#define HDIM 4096

__device__ __forceinline__ float f16tof32(u16 h) {
  _Float16 x;
  __builtin_memcpy(&x, &h, 2);
  return (float)x;
}
__device__ __forceinline__ u16 f32tof16(float f) {
  _Float16 x = (_Float16)f;   // RNE
  u16 h;
  __builtin_memcpy(&h, &x, 2);
  return h;
}

// Interleaved operand layout (A and B both produced by our kernels):
// row-major 4096B rows of 32 K-tiles x 128B; within a tile, chunk c = p*4+q4
// (16B) holds lane (.,q4)'s fragment bytes for half p. K-permutation identical
// for A and B -> any self-consistent HW K-mapping gives the same dot product
// (HW scales fed as 1.0).

__device__ __forceinline__ void gload_lds16(const void* g, void* l) {
  __builtin_amdgcn_global_load_lds((const __attribute__((address_space(1))) void*)g,
                                   (__attribute__((address_space(3))) void*)l, 16, 0, 0);
}

// ---- weight convert + transpose: W[k][n] f32 -> WT[n][k-interleaved] fp8 ----
__global__ __launch_bounds__(256) void k_wconv(const float* __restrict__ w0,
                                               const float* __restrict__ w1,
                                               const float* __restrict__ w2,
                                               u8* __restrict__ out) {
  __shared__ float tl[64][68];
  const int tid = threadIdx.x;
  const int bn = blockIdx.x, bk = blockIdx.y, z = blockIdx.z;
  const float* W = (z == 0) ? w0 : (z == 1 ? w1 : w2);
  u8* o = out + (size_t)z * 16 * MBYTE;
#pragma unroll
  for (int it = 0; it < 4; ++it) {
    int idx = it * 256 + tid;
    int r = idx >> 4, c4 = idx & 15;
    f32x4 v = *(const f32x4*)(W + (size_t)(bk * 64 + r) * HDIM + bn * 64 + c4 * 4);
    *(f32x4*)&tl[r][c4 * 4] = v;
  }
  __syncthreads();
  {
    int n = tid >> 2, q4 = tid & 3;
    u32 dw[4];
#pragma unroll
    for (int d = 0; d < 4; ++d) {
      int k0 = (d >> 1) * 32 + q4 * 8 + (d & 1) * 4;
      int w = __builtin_amdgcn_cvt_pk_fp8_f32(tl[k0 + 0][n], tl[k0 + 1][n], 0, false);
      w = __builtin_amdgcn_cvt_pk_fp8_f32(tl[k0 + 2][n], tl[k0 + 3][n], w, true);
      dw[d] = (u32)w;
    }
    u32x4 pack = {dw[0], dw[1], dw[2], dw[3]};
    *(u32x4*)(o + (size_t)(bn * 64 + n) * HDIM + (bk >> 1) * 128 + (bk & 1) * 64 + q4 * 16) = pack;
  }
}

// ---- fused elementwise ----
// MODE 0: in = x f32 -> relu -> write z f16 (residual init) + rms+quant -> q
// MODE 1: in = z f16 -> rms+quant -> q
// MODE 2: in = z f16 -> rms -> yout f32
template <int MODE>
__global__ __launch_bounds__(256) void k_norm(const void* __restrict__ in_,
                                              u16* __restrict__ zout,
                                              const float* __restrict__ nw,
                                              u32* __restrict__ qout,
                                              float* __restrict__ asct,
                                              float* __restrict__ yout) {
  const int row = blockIdx.x, t = threadIdx.x;
  f32x4 v[4];
  float ss = 0.f;
#pragma unroll
  for (int j = 0; j < 4; ++j) {
    f32x4 a;
    if (MODE == 0) {
      const f32x4* inr = (const f32x4*)((const float*)in_ + (size_t)row * HDIM);
      a = inr[j * 256 + t];
      a.x = fmaxf(a.x, 0.f); a.y = fmaxf(a.y, 0.f);
      a.z = fmaxf(a.z, 0.f); a.w = fmaxf(a.w, 0.f);
      u16x4 rw;
      rw.x = f32tof16(a.x); rw.y = f32tof16(a.y);
      rw.z = f32tof16(a.z); rw.w = f32tof16(a.w);
      ((u16x4*)(zout + (size_t)row * HDIM))[j * 256 + t] = rw;
    } else {
      const u16x4* inr = (const u16x4*)((const u16*)in_ + (size_t)row * HDIM);
      u16x4 iv = inr[j * 256 + t];
      a.x = f16tof32(iv.x); a.y = f16tof32(iv.y);
      a.z = f16tof32(iv.z); a.w = f16tof32(iv.w);
    }
    v[j] = a;
    ss += a.x * a.x + a.y * a.y + a.z * a.z + a.w * a.w;
  }
#pragma unroll
  for (int m = 1; m <= 32; m <<= 1) ss += __shfl_xor(ss, m, 64);
  __shared__ float sred[4];
  if ((t & 63) == 0) sred[t >> 6] = ss;
  __syncthreads();
  float tot = sred[0] + sred[1] + sred[2] + sred[3];
  float rinv = rsqrtf(tot * (1.f / (float)HDIM) + 1e-6f);
#pragma unroll
  for (int j = 0; j < 4; ++j) {
    f32x4 nv = ((const f32x4*)nw)[j * 256 + t];
    f32x4 y;
    y.x = v[j].x * rinv * nv.x; y.y = v[j].y * rinv * nv.y;
    y.z = v[j].z * rinv * nv.z; y.w = v[j].w * rinv * nv.w;
    if (MODE == 2) {
      ((f32x4*)yout)[(size_t)row * 1024 + j * 256 + t] = y;
    } else {
      float am = fmaxf(fmaxf(fabsf(y.x), fabsf(y.y)), fmaxf(fabsf(y.z), fabsf(y.w)));
#pragma unroll
      for (int m = 1; m <= 16; m <<= 1) am = fmaxf(am, __shfl_xor(am, m, 64));
      am = fmaxf(am, 1e-12f);
      float scale = am / 448.f;
      float inv = 448.f / am;
      int d = __builtin_amdgcn_cvt_pk_fp8_f32(y.x * inv, y.y * inv, 0, false);
      d = __builtin_amdgcn_cvt_pk_fp8_f32(y.z * inv, y.w * inv, d, true);
      // interleaved layout: permute u32 index within each 32-u32 (128B) K-tile
      int k4 = j * 256 + t;
      int k4w = k4 & 31;
      int k4n = (k4 & ~31) | (((k4w >> 4) & 1) << 4) | (((k4w >> 1) & 3) << 2)
              | (((k4w >> 3) & 1) << 1) | (k4w & 1);
      qout[(size_t)row * 1024 + k4n] = (u32)d;
      if ((t & 31) == 0) asct[(size_t)(j * 8 + (t >> 5)) * TTOK + row] = scale;
    }
  }
}

// ---- fp8 block-scaled GEMM, 128x128 tile, 4 waves of 64x64, BK=128, MX-rate MFMA.
// R19 champion schedule + A-DIRECT: A fragments are loaded straight from global
// into registers (single-buffered aA, 8 dwordx4/kt), issued one full body
// (~2800 cyc) before use — right after their last read in the previous body.
// Only B goes through LDS (dbuf, gload_lds, swizzle). Top-of-body vmcnt(4)
// retires B-stage(kt) + A(kt) and leaves B-stage(kt+1) in flight. LDS reads
// drop 20 -> 12 b128/wave/kt. Arch regs ~120 <= 128 granule (no spill).
__global__ __launch_bounds__(256, 2) void k_gemm(const u8* __restrict__ A,    // [T][4096] fp8 interleaved
                                                 const u8* __restrict__ B,    // [4096][4096] fp8 interleaved
                                                 const float* __restrict__ aS, // [32][T]
                                                 const float* __restrict__ bS, // [32][32]
                                                 const u16* __restrict__ resid, // [T][4096] f16
                                                 u16* __restrict__ Z) {         // [T][4096] f16
  __shared__ u8 Bl[2][128 * 128];       // 32KB
  __shared__ float As[32 * 128];        // 16KB combined scales [kt][row] = aS*wsb
  const int tid = threadIdx.x;
  const int lane = tid & 63, wave = tid >> 6;
  // XCD chunk (bijective: 4096 blocks, 8 XCDs, 512/chunk) + 2bm x 4bn supertiles
  const int lin = blockIdx.x;
  const int xcd = lin & 7, tt = lin >> 3;
  const int sidx = tt >> 3, rr = tt & 7;        // 64 supertiles of 8 blocks
  const int sm = sidx >> 3, sn = sidx & 7;      // supertile coords (8 x 8)
  const int bm = xcd * 16 + sm * 2 + (rr >> 2); // 16 bm rows per XCD
  const int bn = sn * 4 + (rr & 3);
  const int brow = bm * 128, bcol = bn * 128;
  const int wrb = (wave >> 1) * 64, wcb = (wave & 1) * 64;   // 64x64 wave tile
  const int r16 = lane & 15, q4 = lane >> 4;
  const int swz3 = r16 & 7;
  const int c0 = (q4 ^ swz3) << 4;        // p=0 chunk for this lane
  const int c1 = ((4 + q4) ^ swz3) << 4;  // p=1 chunk

  // B staging (256 thr): pass i covers rows i*32 + (tid>>3), chunk (tid&7), inverse-swizzled
  const int srow = tid >> 3;
  const int scol = (((tid & 7) ^ (srow & 7)) << 4);
  const u8* bP = B + (size_t)(bcol + srow) * HDIM + scol;
  const int ldst = tid * 16;

  // BSTAGE = 4 vmem instructions per wave, 16KB total
#define BSTAGE(c, kt) do {                                                      \
    _Pragma("unroll")                                                           \
    for (int i = 0; i < 4; ++i)                                                 \
      gload_lds16(bP + (size_t)(kt) * 128 + (size_t)i * 32 * HDIM,              \
                  &Bl[c][i * 4096 + ldst]);                                     \
  } while (0)

  // A direct-fragment base: lane (r16,q4), row-block m -> raw chunks q4*16, +64
  const u8* aD = A + (size_t)(brow + wrb + r16) * HDIM + q4 * 16;

#define APREF(kt) do {                                                          \
    _Pragma("unroll")                                                           \
    for (int m = 0; m < 4; ++m) {                                               \
      const u8* p_ = aD + (size_t)m * 16 * HDIM + (size_t)(kt) * 128;           \
      aA[2 * m]     = *(const i32x4*)(p_);                                      \
      aA[2 * m + 1] = *(const i32x4*)(p_ + 64);                                 \
    }                                                                           \
  } while (0)

  // prologue: scale loads (8), BSTAGE0 (4), A0 (8), BSTAGE1 (4)
  const int kt_ = (tid >> 5);            // thread covers kts kt_ + {0,8,16,24}
  const int r_ = (tid & 31) * 4;
  float bv[4];
  f32x4 av[4];
#pragma unroll
  for (int i = 0; i < 4; ++i)
    bv[i] = bS[(i * 8 + kt_) * 32 + bn];
#pragma unroll
  for (int i = 0; i < 4; ++i)
    av[i] = *(const f32x4*)(aS + (size_t)(i * 8 + kt_) * TTOK + brow + r_);
  i32x4 aA[8];
  BSTAGE(0, 0);
  APREF(0);
  BSTAGE(1, 1);                                  // FIFO: 8 scale + 4 B0 + 8 A0 + 4 B1
  asm volatile("s_waitcnt vmcnt(16)" ::: "memory");   // scale loads retired
#pragma unroll
  for (int i = 0; i < 4; ++i) {
    av[i] *= bv[i];
    *(f32x4*)&As[i * 1024 + tid * 4] = av[i];
  }
  asm volatile("s_waitcnt lgkmcnt(0)" ::: "memory");  // As visible after barrier

  f32x4 accm[4][4] = {};
  const f32x4 z4 = {0.f, 0.f, 0.f, 0.f};

#pragma unroll 1
  for (int kt = 0; kt < 32; ++kt) {
    const int cur = kt & 1;
    // retire B-stage(kt) + A(kt); leave B-stage(kt+1) in flight
    if (kt < 31) asm volatile("s_waitcnt vmcnt(4)" ::: "memory");
    else         asm volatile("s_waitcnt vmcnt(0)" ::: "memory");
    __builtin_amdgcn_s_barrier();
    __builtin_amdgcn_sched_barrier(0);   // nothing hoists above the barrier

    i32x8 bfr[4];
#pragma unroll
    for (int n = 0; n < 4; ++n) {
      const u8* rp = &Bl[cur][(wcb + n * 16 + r16) * 128];
      i32x4 lo = *(const i32x4*)(rp + c0);
      i32x4 hi = *(const i32x4*)(rp + c1);
      bfr[n] = __builtin_shufflevector(lo, hi, 0, 1, 2, 3, 4, 5, 6, 7);
    }

#pragma unroll
    for (int m = 0; m < 4; ++m) {
      i32x8 afr = __builtin_shufflevector(aA[2 * m], aA[2 * m + 1],
                                          0, 1, 2, 3, 4, 5, 6, 7);
      const f32x4 s = *(const f32x4*)&As[kt * 128 + wrb + m * 16 + q4 * 4];
      f32x4 acc[4];
      __builtin_amdgcn_s_setprio(1);
#pragma unroll
      for (int n = 0; n < 4; ++n)
        acc[n] = __builtin_amdgcn_mfma_scale_f32_16x16x128_f8f6f4(
            afr, bfr[n], z4, 0, 0, 0, 0x7F7F7F7F, 0, 0x7F7F7F7F);
      __builtin_amdgcn_s_setprio(0);
#pragma unroll
      for (int n = 0; n < 4; ++n)
        accm[m][n] += acc[n] * s;
    }

    // aA fully consumed -> prefetch A(kt+1) into the same registers (WAR-safe,
    // issued one full body before its use; covered by next body's vmcnt(4))
    if (kt < 31) APREF(kt + 1);

    __builtin_amdgcn_sched_barrier(0);   // all Bl[cur] reads stay above barrier2
    __builtin_amdgcn_s_barrier();        // all waves done reading Bl[cur]
    if (kt < 30) BSTAGE(cur, kt + 2);    // overwrite Bl[cur] with tile kt+2
  }
#undef BSTAGE
#undef APREF

  // epilogue: z = C + resid (f16 in, f16 out)
#pragma unroll
  for (int m = 0; m < 4; ++m) {
#pragma unroll
    for (int r = 0; r < 4; ++r) {
      const size_t rowi = (size_t)(brow + wrb + m * 16 + q4 * 4 + r);
      const u16* Rp = resid + rowi * HDIM + bcol + wcb + r16;
      u16* Zp = Z + rowi * HDIM + bcol + wcb + r16;
#pragma unroll
      for (int n = 0; n < 4; ++n)
        Zp[n * 16] = f32tof16(accm[m][n][r] + f16tof32(Rp[n * 16]));
    }
  }
}

extern "C" void kernel_launch(void* const* d_in, const int* in_sizes, int n_in,
                              void* d_out, int out_size, void* d_ws, size_t ws_size,
                              hipStream_t stream) {
  const float* x  = (const float*)d_in[0];
  const float* nw = (const float*)d_in[1];
  const float* w0 = (const float*)d_in[2];
  const float* w1 = (const float*)d_in[3];
  const float* w2 = (const float*)d_in[4];
  const float* s0 = (const float*)d_in[5];
  const float* s1 = (const float*)d_in[6];
  const float* s2 = (const float*)d_in[7];
  float* out = (float*)d_out;
  char* ws = (char*)d_ws;

  u8*  wqt   = (u8*)ws;                               // 3 x 16MB
  u32* q     = (u32*)(ws + (size_t)48 * MBYTE);       // 64MB fp8 activations
  float* asc = (float*)(ws + (size_t)112 * MBYTE);    // 2MB  [32][T]
  u16* zA    = (u16*)(ws + (size_t)114 * MBYTE);      // 128MB f16
  u16* zB    = (u16*)(ws + (size_t)242 * MBYTE);      // 128MB f16

  k_wconv<<<dim3(64, 64, 3), 256, 0, stream>>>(w0, w1, w2, wqt);

  // layer 1: relu(x) -> zA (resid) + quant; z1 = C1 + zA -> zB
  k_norm<0><<<TTOK, 256, 0, stream>>>(x, zA, nw, q, asc, nullptr);
  k_gemm<<<4096, 256, 0, stream>>>((const u8*)q, wqt, asc, s0, zA, zB);

  // layer 2: quant(rms(zB)); z2 = C2 + zB -> zA
  k_norm<1><<<TTOK, 256, 0, stream>>>(zB, nullptr, nw + HDIM, q, asc, nullptr);
  k_gemm<<<4096, 256, 0, stream>>>((const u8*)q, wqt + (size_t)16 * MBYTE, asc, s1, zB, zA);

  // layer 3: quant(rms(zA)); z3 = C3 + zA -> zB
  k_norm<1><<<TTOK, 256, 0, stream>>>(zA, nullptr, nw + 2 * HDIM, q, asc, nullptr);
  k_gemm<<<4096, 256, 0, stream>>>((const u8*)q, wqt + (size_t)32 * MBYTE, asc, s2, zA, zB);

  // final: out = rms(zB) f32
  k_norm<2><<<TTOK, 256, 0, stream>>>(zB, nullptr, nw + 3 * HDIM, nullptr, nullptr, out);
}

// Round 21
// 1285.213 us; speedup vs baseline: 1.5900x; 1.5900x over previous
//
#include <hip/hip_runtime.h>

typedef __attribute__((ext_vector_type(4))) float f32x4;
typedef __attribute__((ext_vector_type(4))) unsigned int u32x4;
typedef __attribute__((ext_vector_type(4))) int i32x4;
typedef __attribute__((ext_vector_type(8))) int i32x8;
typedef __attribute__((ext_vector_type(4))) unsigned short u16x4;
typedef unsigned char u8;
typedef unsigned short u16;
typedef unsigned int u32;

#define MBYTE (1024*1024)
#define TTOK 16384
#define HDIM 4096

__device__ __forceinline__ float f16tof32(u16 h) {
  _Float16 x;
  __builtin_memcpy(&x, &h, 2);
  return (float)x;
}
__device__ __forceinline__ u16 f32tof16(float f) {
  _Float16 x = (_Float16)f;   // RNE
  u16 h;
  __builtin_memcpy(&h, &x, 2);
  return h;
}

// Interleaved operand layout (A and B both produced by our kernels):
// row-major 4096B rows of 32 K-tiles x 128B; within a tile, chunk c = p*4+q4
// (16B) holds lane (.,q4)'s fragment bytes for half p. K-permutation identical
// for A and B -> any self-consistent HW K-mapping gives the same dot product
// (HW scales fed as 1.0).

__device__ __forceinline__ void gload_lds16(const void* g, void* l) {
  __builtin_amdgcn_global_load_lds((const __attribute__((address_space(1))) void*)g,
                                   (__attribute__((address_space(3))) void*)l, 16, 0, 0);
}

// ---- weight convert + transpose: W[k][n] f32 -> WT[n][k-interleaved] fp8 ----
__global__ __launch_bounds__(256) void k_wconv(const float* __restrict__ w0,
                                               const float* __restrict__ w1,
                                               const float* __restrict__ w2,
                                               u8* __restrict__ out) {
  __shared__ float tl[64][68];
  const int tid = threadIdx.x;
  const int bn = blockIdx.x, bk = blockIdx.y, z = blockIdx.z;
  const float* W = (z == 0) ? w0 : (z == 1 ? w1 : w2);
  u8* o = out + (size_t)z * 16 * MBYTE;
#pragma unroll
  for (int it = 0; it < 4; ++it) {
    int idx = it * 256 + tid;
    int r = idx >> 4, c4 = idx & 15;
    f32x4 v = *(const f32x4*)(W + (size_t)(bk * 64 + r) * HDIM + bn * 64 + c4 * 4);
    *(f32x4*)&tl[r][c4 * 4] = v;
  }
  __syncthreads();
  {
    int n = tid >> 2, q4 = tid & 3;
    u32 dw[4];
#pragma unroll
    for (int d = 0; d < 4; ++d) {
      int k0 = (d >> 1) * 32 + q4 * 8 + (d & 1) * 4;
      int w = __builtin_amdgcn_cvt_pk_fp8_f32(tl[k0 + 0][n], tl[k0 + 1][n], 0, false);
      w = __builtin_amdgcn_cvt_pk_fp8_f32(tl[k0 + 2][n], tl[k0 + 3][n], w, true);
      dw[d] = (u32)w;
    }
    u32x4 pack = {dw[0], dw[1], dw[2], dw[3]};
    *(u32x4*)(o + (size_t)(bn * 64 + n) * HDIM + (bk >> 1) * 128 + (bk & 1) * 64 + q4 * 16) = pack;
  }
}

// ---- fused elementwise ----
// MODE 0: in = x f32 -> relu -> write z f16 (residual init) + rms+quant -> q
// MODE 1: in = z f16 -> rms+quant -> q
// MODE 2: in = z f16 -> rms -> yout f32
template <int MODE>
__global__ __launch_bounds__(256) void k_norm(const void* __restrict__ in_,
                                              u16* __restrict__ zout,
                                              const float* __restrict__ nw,
                                              u32* __restrict__ qout,
                                              float* __restrict__ asct,
                                              float* __restrict__ yout) {
  const int row = blockIdx.x, t = threadIdx.x;
  f32x4 v[4];
  float ss = 0.f;
#pragma unroll
  for (int j = 0; j < 4; ++j) {
    f32x4 a;
    if (MODE == 0) {
      const f32x4* inr = (const f32x4*)((const float*)in_ + (size_t)row * HDIM);
      a = inr[j * 256 + t];
      a.x = fmaxf(a.x, 0.f); a.y = fmaxf(a.y, 0.f);
      a.z = fmaxf(a.z, 0.f); a.w = fmaxf(a.w, 0.f);
      u16x4 rw;
      rw.x = f32tof16(a.x); rw.y = f32tof16(a.y);
      rw.z = f32tof16(a.z); rw.w = f32tof16(a.w);
      ((u16x4*)(zout + (size_t)row * HDIM))[j * 256 + t] = rw;
    } else {
      const u16x4* inr = (const u16x4*)((const u16*)in_ + (size_t)row * HDIM);
      u16x4 iv = inr[j * 256 + t];
      a.x = f16tof32(iv.x); a.y = f16tof32(iv.y);
      a.z = f16tof32(iv.z); a.w = f16tof32(iv.w);
    }
    v[j] = a;
    ss += a.x * a.x + a.y * a.y + a.z * a.z + a.w * a.w;
  }
#pragma unroll
  for (int m = 1; m <= 32; m <<= 1) ss += __shfl_xor(ss, m, 64);
  __shared__ float sred[4];
  if ((t & 63) == 0) sred[t >> 6] = ss;
  __syncthreads();
  float tot = sred[0] + sred[1] + sred[2] + sred[3];
  float rinv = rsqrtf(tot * (1.f / (float)HDIM) + 1e-6f);
#pragma unroll
  for (int j = 0; j < 4; ++j) {
    f32x4 nv = ((const f32x4*)nw)[j * 256 + t];
    f32x4 y;
    y.x = v[j].x * rinv * nv.x; y.y = v[j].y * rinv * nv.y;
    y.z = v[j].z * rinv * nv.z; y.w = v[j].w * rinv * nv.w;
    if (MODE == 2) {
      ((f32x4*)yout)[(size_t)row * 1024 + j * 256 + t] = y;
    } else {
      float am = fmaxf(fmaxf(fabsf(y.x), fabsf(y.y)), fmaxf(fabsf(y.z), fabsf(y.w)));
#pragma unroll
      for (int m = 1; m <= 16; m <<= 1) am = fmaxf(am, __shfl_xor(am, m, 64));
      am = fmaxf(am, 1e-12f);
      float scale = am / 448.f;
      float inv = 448.f / am;
      int d = __builtin_amdgcn_cvt_pk_fp8_f32(y.x * inv, y.y * inv, 0, false);
      d = __builtin_amdgcn_cvt_pk_fp8_f32(y.z * inv, y.w * inv, d, true);
      // interleaved layout: permute u32 index within each 32-u32 (128B) K-tile
      int k4 = j * 256 + t;
      int k4w = k4 & 31;
      int k4n = (k4 & ~31) | (((k4w >> 4) & 1) << 4) | (((k4w >> 1) & 3) << 2)
              | (((k4w >> 3) & 1) << 1) | (k4w & 1);
      qout[(size_t)row * 1024 + k4n] = (u32)d;
      if ((t & 31) == 0) asct[(size_t)(j * 8 + (t >> 5)) * TTOK + row] = scale;
    }
  }
}

// ---- fp8 block-scaled GEMM, 128x128 tile, 8 waves of 32x64, BK=128, MX-rate MFMA.
// R19 champion schedule with ONE variable changed: 8 waves (512 thr) instead of
// 4 — 4 waves/SIMD of TLP to hide the barrier/LDS ramps (R5's old 8-wave run was
// confounded by per-kt aS vector loads in the VM FIFO; that confound is gone
// since As lives in LDS). Everything else identical: A+B dbuf gload_lds,
// counted vmcnt(4) (=4 stage instr/wave), 2 barriers/kt, setprio, supertile
// mapping, pre-folded scales, fused residual-add epilogue.
__global__ __launch_bounds__(512, 4) void k_gemm(const u8* __restrict__ A,    // [T][4096] fp8 interleaved
                                                 const u8* __restrict__ B,    // [4096][4096] fp8 interleaved
                                                 const float* __restrict__ aS, // [32][T]
                                                 const float* __restrict__ bS, // [32][32]
                                                 const u16* __restrict__ resid, // [T][4096] f16
                                                 u16* __restrict__ Z) {         // [T][4096] f16
  __shared__ u8 Al[2][128 * 128];
  __shared__ u8 Bl[2][128 * 128];
  __shared__ float As[32 * 128];        // per-block combined scales [kt][row] = aS*wsb
  const int tid = threadIdx.x;
  const int lane = tid & 63, wave = tid >> 6;
  // XCD chunk (bijective: 4096 blocks, 8 XCDs, 512/chunk) + 2bm x 4bn supertiles
  const int lin = blockIdx.x;
  const int xcd = lin & 7, tt = lin >> 3;
  const int sidx = tt >> 3, rr = tt & 7;        // 64 supertiles of 8 blocks
  const int sm = sidx >> 3, sn = sidx & 7;      // supertile coords (8 x 8)
  const int bm = xcd * 16 + sm * 2 + (rr >> 2); // 16 bm rows per XCD
  const int bn = sn * 4 + (rr & 3);
  const int brow = bm * 128, bcol = bn * 128;
  const int wrb = (wave >> 1) * 32, wcb = (wave & 1) * 64;   // 32x64 wave tile
  const int r16 = lane & 15, q4 = lane >> 4;
  const int swz3 = r16 & 7;
  const int c0 = (q4 ^ swz3) << 4;        // p=0 chunk for this lane
  const int c1 = ((4 + q4) ^ swz3) << 4;  // p=1 chunk

  // staging (512 thr): pass i covers rows i*64 + (tid>>3), chunk (tid&7), inverse-swizzled
  const int srow = tid >> 3;
  const int scol = (((tid & 7) ^ (srow & 7)) << 4);   // row&7 invariant across passes (64%8==0)
  const u8* aP = A + (size_t)(brow + srow) * HDIM + scol;
  const u8* bP = B + (size_t)(bcol + srow) * HDIM + scol;
  const int ldst = tid * 16;

  // STAGE = 4 vmem instructions per thread (2 A + 2 B), 32KB total
#define STAGE(c, kt) do {                                                       \
    _Pragma("unroll")                                                           \
    for (int i = 0; i < 2; ++i) {                                               \
      gload_lds16(aP + (size_t)(kt) * 128 + (size_t)i * 64 * HDIM,              \
                  &Al[c][i * 8192 + ldst]);                                     \
      gload_lds16(bP + (size_t)(kt) * 128 + (size_t)i * 64 * HDIM,              \
                  &Bl[c][i * 8192 + ldst]);                                     \
    }                                                                           \
  } while (0)

  // prologue: scale loads (1 bS + 2 aS vmem), stages, fold, park into LDS.
  // thread t covers kt0 = t>>4, rows (t&15)*8 .. +7  (512 thr x 8 floats = 4096)
  const int kt0 = tid >> 4;
  const int r0s = (tid & 15) * 8;
  float bv = bS[kt0 * 32 + bn];
  f32x4 av0 = *(const f32x4*)(aS + (size_t)kt0 * TTOK + brow + r0s);
  f32x4 av1 = *(const f32x4*)(aS + (size_t)kt0 * TTOK + brow + r0s + 4);
  STAGE(0, 0);
  STAGE(1, 1);                                   // FIFO: 3 scale + 8 stage
  asm volatile("s_waitcnt vmcnt(8)" ::: "memory");    // scale loads retired
  av0 *= bv; av1 *= bv;
  *(f32x4*)&As[kt0 * 128 + r0s] = av0;
  *(f32x4*)&As[kt0 * 128 + r0s + 4] = av1;
  asm volatile("s_waitcnt lgkmcnt(0)" ::: "memory");  // As visible after barrier

  f32x4 accm[2][4] = {};
  const f32x4 z4 = {0.f, 0.f, 0.f, 0.f};

#pragma unroll 1
  for (int kt = 0; kt < 32; ++kt) {
    const int cur = kt & 1;
    // tile kt's 4 stage loads are oldest; tile kt+1's 4 stay in flight
    if (kt < 31) asm volatile("s_waitcnt vmcnt(4)" ::: "memory");
    else         asm volatile("s_waitcnt vmcnt(0)" ::: "memory");
    __builtin_amdgcn_s_barrier();
    __builtin_amdgcn_sched_barrier(0);   // nothing hoists above the barrier

    i32x8 bfr[4];
#pragma unroll
    for (int n = 0; n < 4; ++n) {
      const u8* rp = &Bl[cur][(wcb + n * 16 + r16) * 128];
      i32x4 lo = *(const i32x4*)(rp + c0);
      i32x4 hi = *(const i32x4*)(rp + c1);
      bfr[n] = __builtin_shufflevector(lo, hi, 0, 1, 2, 3, 4, 5, 6, 7);
    }

#pragma unroll
    for (int m = 0; m < 2; ++m) {
      const u8* rp = &Al[cur][(wrb + m * 16 + r16) * 128];
      i32x4 lo = *(const i32x4*)(rp + c0);
      i32x4 hi = *(const i32x4*)(rp + c1);
      i32x8 afr = __builtin_shufflevector(lo, hi, 0, 1, 2, 3, 4, 5, 6, 7);
      const f32x4 s = *(const f32x4*)&As[kt * 128 + wrb + m * 16 + q4 * 4];
      f32x4 acc[4];
      __builtin_amdgcn_s_setprio(1);
#pragma unroll
      for (int n = 0; n < 4; ++n)
        acc[n] = __builtin_amdgcn_mfma_scale_f32_16x16x128_f8f6f4(
            afr, bfr[n], z4, 0, 0, 0, 0x7F7F7F7F, 0, 0x7F7F7F7F);
      __builtin_amdgcn_s_setprio(0);
#pragma unroll
      for (int n = 0; n < 4; ++n)
        accm[m][n] += acc[n] * s;
    }

    __builtin_amdgcn_sched_barrier(0);   // all buf[cur] reads stay above barrier2
    __builtin_amdgcn_s_barrier();        // all waves done reading buf[cur]
    if (kt < 30) STAGE(cur, kt + 2);     // overwrite buf[cur] with tile kt+2
  }
#undef STAGE

  // epilogue: z = C + resid (f16 in, f16 out)
#pragma unroll
  for (int m = 0; m < 2; ++m) {
#pragma unroll
    for (int r = 0; r < 4; ++r) {
      const size_t rowi = (size_t)(brow + wrb + m * 16 + q4 * 4 + r);
      const u16* Rp = resid + rowi * HDIM + bcol + wcb + r16;
      u16* Zp = Z + rowi * HDIM + bcol + wcb + r16;
#pragma unroll
      for (int n = 0; n < 4; ++n)
        Zp[n * 16] = f32tof16(accm[m][n][r] + f16tof32(Rp[n * 16]));
    }
  }
}

extern "C" void kernel_launch(void* const* d_in, const int* in_sizes, int n_in,
                              void* d_out, int out_size, void* d_ws, size_t ws_size,
                              hipStream_t stream) {
  const float* x  = (const float*)d_in[0];
  const float* nw = (const float*)d_in[1];
  const float* w0 = (const float*)d_in[2];
  const float* w1 = (const float*)d_in[3];
  const float* w2 = (const float*)d_in[4];
  const float* s0 = (const float*)d_in[5];
  const float* s1 = (const float*)d_in[6];
  const float* s2 = (const float*)d_in[7];
  float* out = (float*)d_out;
  char* ws = (char*)d_ws;

  u8*  wqt   = (u8*)ws;                               // 3 x 16MB
  u32* q     = (u32*)(ws + (size_t)48 * MBYTE);       // 64MB fp8 activations
  float* asc = (float*)(ws + (size_t)112 * MBYTE);    // 2MB  [32][T]
  u16* zA    = (u16*)(ws + (size_t)114 * MBYTE);      // 128MB f16
  u16* zB    = (u16*)(ws + (size_t)242 * MBYTE);      // 128MB f16

  k_wconv<<<dim3(64, 64, 3), 256, 0, stream>>>(w0, w1, w2, wqt);

  // layer 1: relu(x) -> zA (resid) + quant; z1 = C1 + zA -> zB
  k_norm<0><<<TTOK, 256, 0, stream>>>(x, zA, nw, q, asc, nullptr);
  k_gemm<<<4096, 512, 0, stream>>>((const u8*)q, wqt, asc, s0, zA, zB);

  // layer 2: quant(rms(zB)); z2 = C2 + zB -> zA
  k_norm<1><<<TTOK, 256, 0, stream>>>(zB, nullptr, nw + HDIM, q, asc, nullptr);
  k_gemm<<<4096, 512, 0, stream>>>((const u8*)q, wqt + (size_t)16 * MBYTE, asc, s1, zB, zA);

  // layer 3: quant(rms(zA)); z3 = C3 + zA -> zB
  k_norm<1><<<TTOK, 256, 0, stream>>>(zA, nullptr, nw + 2 * HDIM, q, asc, nullptr);
  k_gemm<<<4096, 512, 0, stream>>>((const u8*)q, wqt + (size_t)32 * MBYTE, asc, s2, zA, zB);

  // final: out = rms(zB) f32
  k_norm<2><<<TTOK, 256, 0, stream>>>(zB, nullptr, nw + 3 * HDIM, nullptr, nullptr, out);
}